// Round 2
// baseline (13.853 us; speedup 1.0000x reference)
//
#include <hip/hip_runtime.h>

// Problem constants (match reference)
constexpr int GROUPS = 256;
constexpr int K = 19;
constexpr int L = 1000;
constexpr int B = 256;
constexpr int T = L - K + 1;   // 982 valid conv positions

// out[b,g] = sum_j w[g,j] * (S[b,j] + S[b,75-j]) + 2*T*bias[g]
//   flat j = c*K+k;  S[b,c*K+k] = sum_{l=k}^{k+T-1} x[b,c,l]
// (revcomp identity: (3-c)*K + (K-1-k) == 75 - j)
__global__ __launch_bounds__(256) void pwm_sum_kernel(
    const float* __restrict__ x,     // (B, 4, L)
    const float* __restrict__ w,     // (GROUPS, 4, K)
    const float* __restrict__ bias,  // (GROUPS,)
    float* __restrict__ out)         // (B, GROUPS)
{
    const int b    = blockIdx.x;
    const int tid  = threadIdx.x;
    const int wave = tid >> 6;   // 0..3 -> channel index
    const int lane = tid & 63;

    __shared__ alignas(16) float S_lds[4 * K];   // flat window sums

    // ---- Phase 0: hoist w row + bias into registers (independent of x;
    //      latency hides under phase 1) ----
    const float4* wg = reinterpret_cast<const float4*>(w + (size_t)tid * 4 * K);
    float4 wreg[K];
    #pragma unroll
    for (int i = 0; i < K; ++i) wreg[i] = wg[i];
    const float bz = bias[tid];

    // ---- Phase 1: per-channel reduction, one wave per channel, float4 ----
    const float*  xc  = x + (size_t)b * 4 * L + (size_t)wave * L;
    const float4* xc4 = reinterpret_cast<const float4*>(xc);   // 250 float4
    float4 a4 = make_float4(0.f, 0.f, 0.f, 0.f);
    #pragma unroll
    for (int i = lane; i < 250; i += 64) {
        const float4 v = xc4[i];
        a4.x += v.x; a4.y += v.y; a4.z += v.z; a4.w += v.w;
    }
    float acc = (a4.x + a4.y) + (a4.z + a4.w);
    #pragma unroll
    for (int off = 32; off > 0; off >>= 1)
        acc += __shfl_xor(acc, off, 64);

    // window sums: S[k] = full - head(k) - tail(K-1-k); loads are L1-hot
    if (lane < K) {
        float head = 0.f;
        for (int l = 0; l < lane; ++l) head += xc[l];
        float tail = 0.f;
        for (int l = lane + T; l < L; ++l) tail += xc[l];
        S_lds[wave * K + lane] = acc - head - tail;
    }
    __syncthreads();

    // ---- Phase 2: dot(w[g], S + reverse(S)) — all LDS reads are
    //      wave-uniform broadcasts (conflict-free) ----
    const float4* S4 = reinterpret_cast<const float4*>(S_lds);
    float o = 0.f;
    #pragma unroll
    for (int i = 0; i < K; ++i) {
        const float4 a = S4[i];
        const float4 r = S4[K - 1 - i];          // flats 72-4i .. 75-4i
        o += wreg[i].x * (a.x + r.w)
           + wreg[i].y * (a.y + r.z)
           + wreg[i].z * (a.z + r.y)
           + wreg[i].w * (a.w + r.x);
    }
    o += bz * (2.0f * (float)T);

    out[(size_t)b * GROUPS + tid] = o;
}

extern "C" void kernel_launch(void* const* d_in, const int* in_sizes, int n_in,
                              void* d_out, int out_size, void* d_ws, size_t ws_size,
                              hipStream_t stream) {
    const float* x    = (const float*)d_in[0];  // (B,4,L) f32
    const float* w    = (const float*)d_in[1];  // (GROUPS,4,K) f32
    const float* bias = (const float*)d_in[2];  // (GROUPS,) f32
    float* out        = (float*)d_out;          // (B,GROUPS) f32

    pwm_sum_kernel<<<B, 256, 0, stream>>>(x, w, bias, out);
}

// Round 3
// 11.539 us; speedup vs baseline: 1.2006x; 1.2006x over previous
//
#include <hip/hip_runtime.h>

// Problem constants (match reference)
constexpr int GROUPS = 256;
constexpr int K = 19;
constexpr int L = 1000;
constexpr int B = 256;
constexpr int T = L - K + 1;   // 982 valid conv positions

// out[b,g] = sum_j w[g,j] * (S[b,j] + S[b,75-j]) + 2*T*bias[g]
//   flat j = c*K+k;  S[b,c*K+k] = sum_{l=k}^{k+T-1} x[b,c,l]
// (revcomp identity: (3-c)*K + (K-1-k) == 75 - j)
__global__ __launch_bounds__(256) void pwm_sum_kernel(
    const float* __restrict__ x,     // (B, 4, L)
    const float* __restrict__ w,     // (GROUPS, 4, K)
    const float* __restrict__ bias,  // (GROUPS,)
    float* __restrict__ out)         // (B, GROUPS)
{
    const int b    = blockIdx.x;
    const int tid  = threadIdx.x;
    const int wave = tid >> 6;   // 0..3 -> channel index
    const int lane = tid & 63;

    __shared__ alignas(16) float S_lds[4 * K];   // flat window sums

    // ---- Phase 1a: ISSUE x loads first (critical path: feeds the barrier).
    //      250 float4 per channel; lanes 0..57 take 4, lanes 58..63 take 3.
    const float*  xc  = x + (size_t)b * 4 * L + (size_t)wave * L;
    const float4* xc4 = reinterpret_cast<const float4*>(xc);
    const float4  v0 = xc4[lane];
    const float4  v1 = xc4[lane + 64];
    const float4  v2 = xc4[lane + 128];
    float4 v3 = make_float4(0.f, 0.f, 0.f, 0.f);
    if (lane < 250 - 192) v3 = xc4[lane + 192];

    // ---- Phase 1b: w row + bias loads issued AFTER x — their ~L2 latency
    //      hides under the reduction/barrier; consumed only in phase 3.
    const float4* wg = reinterpret_cast<const float4*>(w + (size_t)tid * 4 * K);
    float4 wreg[K];
    #pragma unroll
    for (int i = 0; i < K; ++i) wreg[i] = wg[i];
    const float bz = bias[tid];

    // ---- Phase 2: reduce channel ----
    float4 a4;
    a4.x = (v0.x + v1.x) + (v2.x + v3.x);
    a4.y = (v0.y + v1.y) + (v2.y + v3.y);
    a4.z = (v0.z + v1.z) + (v2.z + v3.z);
    a4.w = (v0.w + v1.w) + (v2.w + v3.w);
    float acc = (a4.x + a4.y) + (a4.z + a4.w);
    #pragma unroll
    for (int off = 32; off > 0; off >>= 1)
        acc += __shfl_xor(acc, off, 64);

    // window sums: S[k] = full - head(k) - tail(K-1-k); loads are L1-hot
    if (lane < K) {
        float head = 0.f;
        for (int l = 0; l < lane; ++l) head += xc[l];
        float tail = 0.f;
        for (int l = lane + T; l < L; ++l) tail += xc[l];
        S_lds[wave * K + lane] = acc - head - tail;
    }
    __syncthreads();

    // ---- Phase 3: dot(w[g], S + reverse(S)) — LDS reads are wave-uniform
    //      broadcasts (conflict-free) ----
    const float4* S4 = reinterpret_cast<const float4*>(S_lds);
    float o = 0.f;
    #pragma unroll
    for (int i = 0; i < K; ++i) {
        const float4 a = S4[i];
        const float4 r = S4[K - 1 - i];          // flats 72-4i .. 75-4i
        o += wreg[i].x * (a.x + r.w)
           + wreg[i].y * (a.y + r.z)
           + wreg[i].z * (a.z + r.y)
           + wreg[i].w * (a.w + r.x);
    }
    o += bz * (2.0f * (float)T);

    out[(size_t)b * GROUPS + tid] = o;
}

extern "C" void kernel_launch(void* const* d_in, const int* in_sizes, int n_in,
                              void* d_out, int out_size, void* d_ws, size_t ws_size,
                              hipStream_t stream) {
    const float* x    = (const float*)d_in[0];  // (B,4,L) f32
    const float* w    = (const float*)d_in[1];  // (GROUPS,4,K) f32
    const float* bias = (const float*)d_in[2];  // (GROUPS,) f32
    float* out        = (float*)d_out;          // (B,GROUPS) f32

    pwm_sum_kernel<<<B, 256, 0, stream>>>(x, w, bias, out);
}